// Round 2
// baseline (702.252 us; speedup 1.0000x reference)
//
#include <hip/hip_runtime.h>
#include <hip/hip_bf16.h>
#include <math.h>

#define NN 50000
#define EE 800000
#define HID 128
#define PED 24
#define IND 64
#define OUTD 64
#define EBLK 128         // edges per edge-kernel block
#define AKS 136          // act LDS k-stride in bf16 (272 B: 16B-aligned, bank-spread)

typedef short bf16x8 __attribute__((ext_vector_type(8)));
typedef float f32x4 __attribute__((ext_vector_type(4)));

// GELU tanh-form via sigmoid: x * sigmoid(1.5957691x + 0.07135481x^3).
// max |err| vs exact-erf GELU ~4e-4 (below bf16 noise); 6 VALU + 1 trans.
__device__ __forceinline__ float gelu_fast(float x) {
    float x2 = x * x;
    float t = __builtin_fmaf(x2, -0.07135481627f, -1.5957691216f);
    float e = __expf(x * t);
    return x * __builtin_amdgcn_rcpf(1.0f + e);
}
__device__ __forceinline__ unsigned short f2bf(float f) {
    unsigned int u = __float_as_uint(f);
    u = (u + 0x7fffu + ((u >> 16) & 1u)) >> 16;   // RNE
    return (unsigned short)u;
}
__device__ __forceinline__ unsigned int pkbf2(float a, float b) {
    __hip_bfloat162 h = __float22bfloat162_rn(make_float2(a, b));  // a -> low
    return *reinterpret_cast<unsigned int*>(&h);
}
__device__ __forceinline__ float bf2f(unsigned short u) {
    return __uint_as_float((unsigned int)u << 16);
}

// ---------------------------------------------------------------------------
// Fused pre-pass:
//   blocks [0, 6250):    xh_bf16 = bf16(x @ W_x + b_x) AND zero wV
//   blocks [6250, 6458): weight transposes WT_* AND zero cnt
// ---------------------------------------------------------------------------
__global__ __launch_bounds__(256) void pre_kernel(
    const float* __restrict__ x, const float* __restrict__ W_x,
    const float* __restrict__ b_x, unsigned short* __restrict__ xhb,
    const float* __restrict__ W_in, const float* __restrict__ W1,
    const float* __restrict__ W2, const float* __restrict__ Wf,
    unsigned short* __restrict__ WT_in, unsigned short* __restrict__ WT1,
    unsigned short* __restrict__ WT2, unsigned short* __restrict__ WTf,
    float* __restrict__ wV, int* __restrict__ cnt) {
    int bx = blockIdx.x;
    if (bx < 6250) {
        int gid = bx * 256 + threadIdx.x;
        int n = gid >> 5;               // 6250*256/32 = 50000 exactly
        int q = gid & 31;
        *(float4*)&wV[(size_t)n * HID + q * 4] = make_float4(0.f, 0.f, 0.f, 0.f);
        const float* xr = x + (size_t)n * IND;
        float4 acc = *(const float4*)&b_x[q * 4];
#pragma unroll 8
        for (int k = 0; k < IND; k++) {
            float xk = xr[k];
            float4 w = *(const float4*)&W_x[k * HID + q * 4];
            acc.x += xk * w.x; acc.y += xk * w.y;
            acc.z += xk * w.z; acc.w += xk * w.w;
        }
        uint2 p;
        p.x = pkbf2(acc.x, acc.y);
        p.y = pkbf2(acc.z, acc.w);
        ((uint2*)&xhb[(size_t)n * HID])[q] = p;
    } else {
        int idx = (bx - 6250) * 256 + threadIdx.x;   // [0, 53248)
        if (idx < NN) cnt[idx] = 0;
        if (idx < 4096) {                       // WT_in [128][32], k>=24 zero-pad
            int j = idx >> 5, k = idx & 31;
            WT_in[idx] = f2bf(k < PED ? W_in[k * HID + j] : 0.f);
        } else if (idx < 4096 + 16384) {
            int i = idx - 4096; int j = i >> 7, k = i & 127;
            WT1[i] = f2bf(W1[k * HID + j]);
        } else if (idx < 4096 + 32768) {
            int i = idx - 4096 - 16384; int j = i >> 7, k = i & 127;
            WT2[i] = f2bf(W2[k * HID + j]);
        } else if (idx < 4096 + 49152) {
            int i = idx - 4096 - 32768; int j = i >> 7, k = i & 127;
            WTf[i] = f2bf(Wf[k * HID + j]);
        }
    }
}

// ---------------------------------------------------------------------------
// CSR build: histogram(tgt) -> exclusive scan -> scatter edge ids
// ---------------------------------------------------------------------------
__global__ __launch_bounds__(256) void hist_kernel(const int* __restrict__ pe_idx,
                                                   int* __restrict__ cnt) {
    int e = blockIdx.x * 256 + threadIdx.x;
    if (e < EE) atomicAdd(&cnt[pe_idx[e]], 1);
}

__global__ __launch_bounds__(1024) void scan_kernel(const int* __restrict__ cnt,
                                                    int* __restrict__ woff) {
    __shared__ int s_w[16];
    int tid = threadIdx.x;
    const int chunk = (NN + 1023) / 1024;
    int base = tid * chunk;
    int end = base + chunk; if (end > NN) end = NN;
    int s = 0;
    for (int i = base; i < end; i++) s += cnt[i];
    int v = s;
    int lane = tid & 63, wid = tid >> 6;
#pragma unroll
    for (int d = 1; d < 64; d <<= 1) {
        int u = __shfl_up(v, d, 64);
        if (lane >= d) v += u;
    }
    if (lane == 63) s_w[wid] = v;
    __syncthreads();
    if (tid < 16) {
        int wv = s_w[tid];
#pragma unroll
        for (int d = 1; d < 16; d <<= 1) {
            int u = __shfl_up(wv, d, 64);
            if (tid >= d) wv += u;
        }
        s_w[tid] = wv;
    }
    __syncthreads();
    int exc = v - s + (wid ? s_w[wid - 1] : 0);
    int run = exc;
    for (int i = base; i < end; i++) { woff[i] = run; run += cnt[i]; }
}

__global__ __launch_bounds__(256) void scatter_kernel(const int* __restrict__ pe_idx,
                                                      int* __restrict__ woff,
                                                      int* __restrict__ perm) {
    int e = blockIdx.x * 256 + threadIdx.x;
    if (e < EE) {
        int t = pe_idx[e];
        int p = atomicAdd(&woff[t], 1);
        perm[p] = e;
    }
}

// ---------------------------------------------------------------------------
// Fused edge MLP (MFMA) + gather-multiply + CSR-sorted segment reduction.
// v3: double-buffered s_act (ping-pong per GEMM round) -> exactly ONE barrier
// per round (5 total, was 11). Weight A-fragments read directly from global
// WT (L1/L2-resident, shared by all blocks) -> no s_W staging, no s_msg:
// the gather-multiply is fused into the segment walk (512 threads = 4
// quarters x 128 channels, u16 loads wave-coalesced to 128B/edge).
// ---------------------------------------------------------------------------
__global__ __launch_bounds__(512, 4) void edge_kernel(
    const float* __restrict__ pe_val, const int* __restrict__ pe_idx,
    const int* __restrict__ perm, const unsigned short* __restrict__ xhb,
    const unsigned short* __restrict__ WT_in, const unsigned short* __restrict__ WT1,
    const unsigned short* __restrict__ WT2, const unsigned short* __restrict__ WTf,
    const float* __restrict__ b_in, const float* __restrict__ b1,
    const float* __restrict__ b2, const float* __restrict__ bfin,
    float* __restrict__ wV) {
    __shared__ __align__(16) unsigned short s_act[2][EBLK][AKS];  // 69.6 KB
    __shared__ int s_tgt[EBLK], s_src[EBLK];

    const int tid = threadIdx.x;
    const int lane = tid & 63;
    const int w = tid >> 6;          // wave 0..7
    const int cg = w & 3;            // channel group (32 ch)
    const int eh = w >> 2;           // edge half (64 edges)
    const int ebase = eh * 64;
    const int l15 = lane & 15;
    const int quad = lane >> 4;
    const long b0 = (long)blockIdx.x * EBLK;

    if (tid < EBLK) {
        int eid = perm[b0 + tid];
        s_tgt[tid] = pe_idx[eid];
        s_src[tid] = pe_idx[EE + eid];
    }
    // stage pe (bf16 pairs) into buf0 cols 0..31 (24..31 zero); perm read
    // redundantly (16 threads/edge, same address -> L2 broadcast)
#pragma unroll
    for (int i = 0; i < 4; i++) {
        int idx = tid + i * 512; int e = idx >> 4, k2 = idx & 15;
        float2 v = make_float2(0.f, 0.f);
        if (k2 < 12) {
            int eid = perm[b0 + e];
            v = *(const float2*)&pe_val[(size_t)eid * PED + k2 * 2];
        }
        *(unsigned int*)&s_act[0][e][k2 * 2] = pkbf2(v.x, v.y);
    }
    __syncthreads();                                   // barrier 1

    f32x4 C[2][4];
    f32x4 x0s[2][4];

    // ---- GEMM1: x0 = pe @ W_in + b_in  (K=32, bias in C-init, W from global)
    {
        float4 ba = *(const float4*)&b_in[(2 * cg + 0) * 16 + quad * 4];
        float4 bb = *(const float4*)&b_in[(2 * cg + 1) * 16 + quad * 4];
        f32x4 ci0 = {ba.x, ba.y, ba.z, ba.w};
        f32x4 ci1 = {bb.x, bb.y, bb.z, bb.w};
        bf16x8 a0 = *(const bf16x8*)&WT_in[((2 * cg + 0) * 16 + l15) * 32 + quad * 8];
        bf16x8 a1 = *(const bf16x8*)&WT_in[((2 * cg + 1) * 16 + l15) * 32 + quad * 8];
#pragma unroll
        for (int u = 0; u < 4; u++) {
            bf16x8 bfr = *(const bf16x8*)&s_act[0][ebase + u * 16 + l15][quad * 8];
            C[0][u] = __builtin_amdgcn_mfma_f32_16x16x32_bf16(a0, bfr, ci0, 0, 0, 0);
            C[1][u] = __builtin_amdgcn_mfma_f32_16x16x32_bf16(a1, bfr, ci1, 0, 0, 0);
        }
    }
    // epi1: save x0, gelu -> buf1  (no WAR: different buffer)
#pragma unroll
    for (int t = 0; t < 2; t++) {
        int ch0 = (2 * cg + t) * 16 + quad * 4;
#pragma unroll
        for (int u = 0; u < 4; u++) {
            int e = ebase + u * 16 + l15;
            f32x4 c = C[t][u];
            x0s[t][u] = c;
            uint2 p;
            p.x = pkbf2(gelu_fast(c[0]), gelu_fast(c[1]));
            p.y = pkbf2(gelu_fast(c[2]), gelu_fast(c[3]));
            *(uint2*)&s_act[1][e][ch0] = p;
        }
    }
    __syncthreads();                                   // barrier 2

    // A-fragments streamed from global WT (row j = (2cg+t)*16+l15, k-minor).
#define GEMM128(WT, BIAS, SB)                                                  \
    {                                                                          \
        float4 ba_ = *(const float4*)&(BIAS)[(2 * cg + 0) * 16 + quad * 4];    \
        float4 bb_ = *(const float4*)&(BIAS)[(2 * cg + 1) * 16 + quad * 4];    \
        f32x4 ci0 = {ba_.x, ba_.y, ba_.z, ba_.w};                              \
        f32x4 ci1 = {bb_.x, bb_.y, bb_.z, bb_.w};                              \
        _Pragma("unroll") for (int u = 0; u < 4; u++) {                        \
            C[0][u] = ci0; C[1][u] = ci1;                                      \
        }                                                                      \
        _Pragma("unroll") for (int ks = 0; ks < 4; ks++) {                     \
            bf16x8 a0 = *(const bf16x8*)&(WT)[((2 * cg + 0) * 16 + l15) * HID  \
                                              + ks * 32 + quad * 8];           \
            bf16x8 a1 = *(const bf16x8*)&(WT)[((2 * cg + 1) * 16 + l15) * HID  \
                                              + ks * 32 + quad * 8];           \
            _Pragma("unroll") for (int u = 0; u < 4; u++) {                    \
                bf16x8 bfr = *(const bf16x8*)&s_act[SB][ebase + u * 16 + l15]  \
                                                   [ks * 32 + quad * 8];       \
                C[0][u] = __builtin_amdgcn_mfma_f32_16x16x32_bf16(a0, bfr,     \
                                                                  C[0][u], 0, 0, 0); \
                C[1][u] = __builtin_amdgcn_mfma_f32_16x16x32_bf16(a1, bfr,     \
                                                                  C[1][u], 0, 0, 0); \
            }                                                                  \
        }                                                                      \
    }

    // ---- GEMM2: h1 = g(x0) @ W1 + b1 ; gelu -> buf0 ----
    GEMM128(WT1, b1, 1);
#pragma unroll
    for (int t = 0; t < 2; t++) {
        int ch0 = (2 * cg + t) * 16 + quad * 4;
#pragma unroll
        for (int u = 0; u < 4; u++) {
            int e = ebase + u * 16 + l15;
            f32x4 c = C[t][u];
            uint2 p;
            p.x = pkbf2(gelu_fast(c[0]), gelu_fast(c[1]));
            p.y = pkbf2(gelu_fast(c[2]), gelu_fast(c[3]));
            *(uint2*)&s_act[0][e][ch0] = p;
        }
    }
    __syncthreads();                                   // barrier 3

    // ---- GEMM3: h2 = g(h1) @ W2 + b2 ; x0' = h2 + x0 -> buf1 ----
    GEMM128(WT2, b2, 0);
#pragma unroll
    for (int t = 0; t < 2; t++) {
        int ch0 = (2 * cg + t) * 16 + quad * 4;
#pragma unroll
        for (int u = 0; u < 4; u++) {
            int e = ebase + u * 16 + l15;
            f32x4 c = C[t][u];
            f32x4 x0 = x0s[t][u];
            uint2 p;
            p.x = pkbf2(c[0] + x0[0], c[1] + x0[1]);
            p.y = pkbf2(c[2] + x0[2], c[3] + x0[3]);
            *(uint2*)&s_act[1][e][ch0] = p;
        }
    }
    __syncthreads();                                   // barrier 4

    // ---- GEMM4: score = x0' @ W_fin + b_fin -> buf0 (bf16) ----
    GEMM128(WTf, bfin, 1);
#pragma unroll
    for (int t = 0; t < 2; t++) {
        int ch0 = (2 * cg + t) * 16 + quad * 4;
#pragma unroll
        for (int u = 0; u < 4; u++) {
            int e = ebase + u * 16 + l15;
            f32x4 c = C[t][u];
            uint2 p;
            p.x = pkbf2(c[0], c[1]);
            p.y = pkbf2(c[2], c[3]);
            *(uint2*)&s_act[0][e][ch0] = p;
        }
    }
    __syncthreads();                                   // barrier 5

    // ---- Fused gather-multiply + segment walk ----
    // 512 threads = 4 quarters (32 edges) x 128 channels. Per edge the wave
    // reads xhb[src*128 + c] (64 consecutive u16 = 128B, coalesced) and the
    // bf16 score from LDS; interior segments (node fully inside quarter) get
    // a plain store, quarter-boundary segments an atomicAdd.
    {
        const int c = tid & 127;
        const int q = tid >> 7;
        const int e0 = q * 32;
        float acc = 0.f;
        int prev = s_tgt[e0];
        bool firstseg = true;
#pragma unroll
        for (int b = 0; b < 4; b++) {
            float xs[8];
#pragma unroll
            for (int j = 0; j < 8; j++) {
                int e = e0 + b * 8 + j;
                xs[j] = bf2f(xhb[(size_t)s_src[e] * HID + c]);
            }
#pragma unroll
            for (int j = 0; j < 8; j++) {
                int e = e0 + b * 8 + j;
                int tg = s_tgt[e];
                if (tg != prev) {
                    if (firstseg) atomicAdd(&wV[(size_t)prev * HID + c], acc);
                    else          wV[(size_t)prev * HID + c] = acc;
                    firstseg = false;
                    acc = 0.f;
                    prev = tg;
                }
                float sc = bf2f(s_act[0][e][c]);
                acc += xs[j] * sc;
            }
        }
        atomicAdd(&wV[(size_t)prev * HID + c], acc);  // last seg may span blocks
    }
#undef GEMM128
}

// ---------------------------------------------------------------------------
// out = (wV / max(deg,1) + head_bias) @ W_out + b_out ; 4 outputs/thread
// ---------------------------------------------------------------------------
__global__ __launch_bounds__(256) void out_kernel(
    const float* __restrict__ wV, const int* __restrict__ cnt,
    const float* __restrict__ head_bias, const float* __restrict__ W_out,
    const float* __restrict__ b_out, float* __restrict__ out) {
    int gid = blockIdx.x * 256 + threadIdx.x;
    int n = gid >> 4;
    int q = gid & 15;
    if (n >= NN) return;
    float inv = 1.0f / fmaxf((float)cnt[n], 1.0f);
    const float* wr = wV + (size_t)n * HID;
    float4 acc = *(const float4*)&b_out[q * 4];
#pragma unroll 4
    for (int k = 0; k < HID; k++) {
        float hv = wr[k] * inv + head_bias[k];
        float4 wv4 = *(const float4*)&W_out[k * OUTD + q * 4];
        acc.x += hv * wv4.x; acc.y += hv * wv4.y;
        acc.z += hv * wv4.z; acc.w += hv * wv4.w;
    }
    *(float4*)&out[(size_t)n * OUTD + q * 4] = acc;
}

extern "C" void kernel_launch(void* const* d_in, const int* in_sizes, int n_in,
                              void* d_out, int out_size, void* d_ws, size_t ws_size,
                              hipStream_t stream) {
    const float* x      = (const float*)d_in[0];
    const int*   pe_idx = (const int*)d_in[1];
    const float* pe_val = (const float*)d_in[2];
    const float* W_in   = (const float*)d_in[3];
    const float* b_in   = (const float*)d_in[4];
    const float* W1     = (const float*)d_in[5];
    const float* b1     = (const float*)d_in[6];
    const float* W2     = (const float*)d_in[7];
    const float* b2     = (const float*)d_in[8];
    const float* Wf     = (const float*)d_in[9];
    const float* bfin   = (const float*)d_in[10];
    const float* W_x    = (const float*)d_in[11];
    const float* b_x    = (const float*)d_in[12];
    const float* hb     = (const float*)d_in[13];
    const float* W_out  = (const float*)d_in[14];
    const float* b_out  = (const float*)d_in[15];
    float* out = (float*)d_out;

    // ws layout:
    // wV f32 [N*128] | cnt i32 [N] | woff i32 [N] | perm i32 [E] |
    // WT_in u16 [4096] | WT1/WT2/WTf u16 [16384 each] | xhb u16 [N*128]
    float* wV   = (float*)d_ws;
    int*   cnt  = (int*)(wV + (size_t)NN * HID);
    int*   woff = cnt + NN;
    int*   perm = woff + NN;
    unsigned short* WT_in = (unsigned short*)(perm + EE);
    unsigned short* WT1   = WT_in + 128 * 32;
    unsigned short* WT2   = WT1 + 128 * 128;
    unsigned short* WTf   = WT2 + 128 * 128;
    unsigned short* xhb   = WTf + 128 * 128;

    pre_kernel<<<6250 + 208, 256, 0, stream>>>(x, W_x, b_x, xhb,
                                               W_in, W1, W2, Wf,
                                               WT_in, WT1, WT2, WTf, wV, cnt);
    hist_kernel<<<(EE + 255) / 256, 256, 0, stream>>>(pe_idx, cnt);
    scan_kernel<<<1, 1024, 0, stream>>>(cnt, woff);
    scatter_kernel<<<(EE + 255) / 256, 256, 0, stream>>>(pe_idx, woff, perm);

    edge_kernel<<<EE / EBLK, 512, 0, stream>>>(pe_val, pe_idx, perm, xhb,
                                               WT_in, WT1, WT2, WTf,
                                               b_in, b1, b2, bfin, wV);

    out_kernel<<<(NN * 16 + 255) / 256, 256, 0, stream>>>(wV, cnt, hb, W_out,
                                                          b_out, out);
}